// Round 7
// baseline (178.747 us; speedup 1.0000x reference)
//
#include <hip/hip_runtime.h>
#include <hip/hip_bf16.h>
#include <cstdint>

typedef __attribute__((ext_vector_type(8))) short short8;
typedef __attribute__((ext_vector_type(16))) float f32x16;

#if __has_builtin(__builtin_amdgcn_exp2f)
#define EXP2F(x) __builtin_amdgcn_exp2f(x)
#else
#define EXP2F(x) exp2f(x)
#endif

#define MFMA32(A, B, C) __builtin_amdgcn_mfma_f32_32x32x16_bf16((A), (B), (C), 0, 0, 0)

// fp32 -> bf16, round-to-nearest-even (proven path)
__device__ __forceinline__ unsigned short f2bf(float f) {
  unsigned int u = __builtin_bit_cast(unsigned int, f);
  u += 0x7FFFu + ((u >> 16) & 1u);
  return (unsigned short)(u >> 16);
}

// pack 8 fp32 (two float4) -> short8 bf16 A-fragment (proven bit pattern)
__device__ __forceinline__ short8 packA(const float4 &a0, const float4 &a1) {
  uint4 uu;
  uu.x = (unsigned int)f2bf(a0.x) | ((unsigned int)f2bf(a0.y) << 16);
  uu.y = (unsigned int)f2bf(a0.z) | ((unsigned int)f2bf(a0.w) << 16);
  uu.z = (unsigned int)f2bf(a1.x) | ((unsigned int)f2bf(a1.y) << 16);
  uu.w = (unsigned int)f2bf(a1.z) | ((unsigned int)f2bf(a1.w) << 16);
  return __builtin_bit_cast(short8, uu);
}

// ---------------------------------------------------------------------------
// Prep: Wt[which][n][k] = f2bf(W_which[k][n]),  3 x 64 x 512 bf16. (proven)
// ---------------------------------------------------------------------------
__global__ __launch_bounds__(256) void prep_wt(
    const float* __restrict__ Wq, const float* __restrict__ Wk,
    const float* __restrict__ Wv, unsigned short* __restrict__ Wt)
{
  int idx = blockIdx.x * 256 + threadIdx.x;     // 384 blocks
  int which = idx >> 15;
  int rem = idx & 32767;
  int n = rem >> 9;
  int k = rem & 511;
  const float* W = (which == 0) ? Wq : (which == 1) ? Wk : Wv;
  Wt[idx] = f2bf(W[k * 64 + n]);
}

// ---------------------------------------------------------------------------
// Projection, round 7: direct-fragment GEMM — NO LDS, NO BARRIERS.
//   r4-r6 post-mortems: every barrier'd LDS-staged variant is stuck at
//   ~1.4 TB/s (17% HBM) because the stage->barrier->compute cycle exposes
//   HBM latency each chunk and the compiler sinks plain prefetch loads
//   (r6: VGPR=48 proves it). Observation: with a 32-row M-tile per wave
//   and the full N=64 owned by that wave, each X row is read by EXACTLY
//   one wave -> LDS staging has zero reuse value. So: lane reads its MFMA
//   A-fragment straight from global (row l31, 8 consecutive fp32 at
//   k0+h*8; h-pairs cover full 64B lines -> clean coalescing), packs to
//   bf16 in-reg, 4-slot software pipeline with named slot registers
//   (anti-deps prevent collapse), zero __syncthreads.
//   B-frags from Wt (bf16, 64KB/matrix, L1/L2-hot): lane = col n, 16B/step.
//   grid (256, 3), block 128 (2 waves, 64 rows) -> 768 blocks, 3/CU.
//   Fragment/C-layout indexing identical to the proven r3 kernel.
// ---------------------------------------------------------------------------
#define PJ_LOAD(S, ks) do { \
    a##S##0 = *(const float4*)(ap + (size_t)(ks) * 16); \
    a##S##1 = *(const float4*)(ap + (size_t)(ks) * 16 + 4); \
    b##S##0 = *(const short8*)(bp0 + (ks) * 16); \
    b##S##1 = *(const short8*)(bp1 + (ks) * 16); \
  } while (0)

#define PJ_STEP(S) do { \
    short8 af = packA(a##S##0, a##S##1); \
    acc0 = MFMA32(af, b##S##0, acc0); \
    acc1 = MFMA32(af, b##S##1, acc1); \
  } while (0)

__global__ __launch_bounds__(128) void proj_kernel(
    const float* __restrict__ qin, const float* __restrict__ kin,
    const float* __restrict__ vin, const unsigned short* __restrict__ Wt,
    const float* __restrict__ bq, const float* __restrict__ bk,
    const float* __restrict__ bv,
    unsigned short* __restrict__ Qo, unsigned short* __restrict__ Ko,
    unsigned short* __restrict__ Vto)
{
  const int which = blockIdx.y;
  const float* X    = (which == 0) ? qin : (which == 1) ? kin : vin;
  const float* bias = (which == 0) ? bq  : (which == 1) ? bk  : bv;

  const int tid = threadIdx.x;
  const int lane = tid & 63, w = tid >> 6;     // 2 waves
  const int h = lane >> 5, l31 = lane & 31;
  const int m0 = (blockIdx.x * 2 + w) * 32;    // wave's 32 X-rows

  // A: lane reads X[m0+l31][ks*16 + h*8 .. +7] (8 fp32) per k-step
  const float* ap = X + (size_t)(m0 + l31) * 512 + h * 8;
  // B: lane reads Wt[which][n][ks*16 + h*8 .. +7] (8 bf16 = 16B) per k-step
  const unsigned short* bp0 = Wt + (size_t)which * 32768 + (size_t)l31 * 512 + h * 8;
  const unsigned short* bp1 = bp0 + 32 * 512;  // n-quadrant 1

  f32x16 acc0 = {}, acc1 = {};

  float4 a00, a01, a10, a11, a20, a21, a30, a31;
  short8 b00, b01, b10, b11, b20, b21, b30, b31;

  PJ_LOAD(0, 0); PJ_LOAD(1, 1); PJ_LOAD(2, 2); PJ_LOAD(3, 3);

  for (int ks = 0; ks < 32; ks += 4) {
    PJ_STEP(0); if (ks + 4 < 32) PJ_LOAD(0, ks + 4);
    PJ_STEP(1); if (ks + 5 < 32) PJ_LOAD(1, ks + 5);
    PJ_STEP(2); if (ks + 6 < 32) PJ_LOAD(2, ks + 6);
    PJ_STEP(3); if (ks + 7 < 32) PJ_LOAD(3, ks + 7);
  }

  const float bi0 = bias[l31];
  const float bi1 = bias[32 + l31];

  if (which < 2) {
    const float scale = which ? 1.0f : 0.18033688f;  // (1/sqrt(64))*log2(e) for Q
    unsigned short* Y = which ? Ko : Qo;
    #pragma unroll
    for (int r = 0; r < 16; ++r) {
      int row = (r & 3) + 8 * (r >> 2) + 4 * h;      // C/D layout [m101]
      Y[(size_t)(m0 + row) * 64 + l31]      = f2bf((acc0[r] + bi0) * scale);
      Y[(size_t)(m0 + row) * 64 + 32 + l31] = f2bf((acc1[r] + bi1) * scale);
    }
  } else {
    // V -> Vto[b][n][s], direct: C-layout's (r&3) gives 4 consecutive s.
    const int bb = m0 >> 11;          // batch
    const int s0 = m0 & 2047;         // s within batch
    #pragma unroll
    for (int g = 0; g < 4; ++g) {
      const int s = s0 + 8 * g + 4 * h;
      ushort4 v0, v1;
      v0.x = f2bf(acc0[4 * g + 0] + bi0); v0.y = f2bf(acc0[4 * g + 1] + bi0);
      v0.z = f2bf(acc0[4 * g + 2] + bi0); v0.w = f2bf(acc0[4 * g + 3] + bi0);
      v1.x = f2bf(acc1[4 * g + 0] + bi1); v1.y = f2bf(acc1[4 * g + 1] + bi1);
      v1.z = f2bf(acc1[4 * g + 2] + bi1); v1.w = f2bf(acc1[4 * g + 3] + bi1);
      *(ushort4*)(Vto + ((size_t)(bb * 64 + l31)) * 2048 + s)      = v0;
      *(ushort4*)(Vto + ((size_t)(bb * 64 + 32 + l31)) * 2048 + s) = v1;
    }
  }
}

// ---------------------------------------------------------------------------
// Flash attention, transposed formulation — exact round-3 proven version:
// tree reductions, defer-max (THR=8), K/V register prefetch, setprio,
// proven shfl_xor/f2bf exchange. 64 queries/block, grid (32,8).
// ---------------------------------------------------------------------------
__global__ __launch_bounds__(512, 2) void attn_kernel(
    const unsigned short* __restrict__ Q, const unsigned short* __restrict__ K,
    const unsigned short* __restrict__ Vt, float* __restrict__ out)
{
  __shared__ float ObS[4][16][64];
  __shared__ float MpS[4][64];
  __shared__ float LpS[4][64];

  const int tid = threadIdx.x;
  const int lane = tid & 63, w = tid >> 6;
  const int h = lane >> 5, l31 = lane & 31;
  const int b = blockIdx.y;
  const int q0 = blockIdx.x * 64;

  short8 qf[2][4];
  #pragma unroll
  for (int qt = 0; qt < 2; ++qt) {
    const unsigned short* qp = Q + ((size_t)(b * 2048 + q0 + qt * 32 + l31)) * 64 + h * 8;
    #pragma unroll
    for (int c = 0; c < 4; ++c) qf[qt][c] = *(const short8*)(qp + c * 16);
  }

  f32x16 o00 = {}, o01 = {}, o10 = {}, o11 = {};
  float m0 = -1e30f, m1 = -1e30f, ls0 = 0.f, ls1 = 0.f;

  const unsigned short* Kp  = K  + ((size_t)(b * 2048 + w * 256 + l31)) * 64 + h * 8;
  const unsigned short* Vp0 = Vt + ((size_t)(b * 64 + l31)) * 2048 + w * 256 + h * 8;
  const unsigned short* Vp1 = Vp0 + (size_t)32 * 2048;

  short8 kf[4], vf0[2], vf1[2];
  #pragma unroll
  for (int c = 0; c < 4; ++c) kf[c] = *(const short8*)(Kp + c * 16);
  vf0[0] = *(const short8*)(Vp0); vf0[1] = *(const short8*)(Vp0 + 16);
  vf1[0] = *(const short8*)(Vp1); vf1[1] = *(const short8*)(Vp1 + 16);

  // softmax + PV for one 32-query tile; sT is S^T[key r][q l31]
  auto process = [&](f32x16 sT, float &m, float &ls, f32x16 &oA, f32x16 &oB) {
    float tm[8];
    #pragma unroll
    for (int i = 0; i < 8; ++i) tm[i] = fmaxf(sT[2 * i], sT[2 * i + 1]);
    #pragma unroll
    for (int i = 0; i < 4; ++i) tm[i] = fmaxf(tm[i], tm[i + 4]);
    float mx = fmaxf(fmaxf(tm[0], tm[1]), fmaxf(tm[2], tm[3]));
    mx = fmaxf(mx, __shfl_xor(mx, 32, 64));
    if (__any(mx > m + 8.0f)) {   // defer-max (log2 domain, P <= 2^8)
      float mnew = fmaxf(m, mx);
      float alpha = EXP2F(m - mnew);
      m = mnew;
      ls *= alpha; oA *= alpha; oB *= alpha;
    }
    float p[16];
    #pragma unroll
    for (int r = 0; r < 16; ++r) p[r] = EXP2F(sT[r] - m);
    float ts[8];
    #pragma unroll
    for (int i = 0; i < 8; ++i) ts[i] = p[2 * i] + p[2 * i + 1];
    #pragma unroll
    for (int i = 0; i < 4; ++i) ts[i] += ts[i + 4];
    float rs = (ts[0] + ts[1]) + (ts[2] + ts[3]);
    rs += __shfl_xor(rs, 32, 64);
    ls += rs;
    unsigned int pk[8];
    #pragma unroll
    for (int i = 0; i < 8; ++i)
      pk[i] = (unsigned int)f2bf(p[2 * i]) | ((unsigned int)f2bf(p[2 * i + 1]) << 16);
    unsigned int ex[8];
    #pragma unroll
    for (int i = 0; i < 8; ++i) ex[i] = (unsigned int)__shfl_xor((int)pk[i], 32, 64);
    uint4 cc0, cc1;
    if (h == 0) { cc0 = make_uint4(pk[0], pk[1], ex[0], ex[1]); cc1 = make_uint4(pk[4], pk[5], ex[4], ex[5]); }
    else        { cc0 = make_uint4(ex[2], ex[3], pk[2], pk[3]); cc1 = make_uint4(ex[6], ex[7], pk[6], pk[7]); }
    short8 P0 = __builtin_bit_cast(short8, cc0);
    short8 P1 = __builtin_bit_cast(short8, cc1);
    __builtin_amdgcn_s_setprio(1);
    oA = MFMA32(vf0[0], P0, oA); oA = MFMA32(vf0[1], P1, oA);
    oB = MFMA32(vf1[0], P0, oB); oB = MFMA32(vf1[1], P1, oB);
    __builtin_amdgcn_s_setprio(0);
  };

  for (int st = 0; st < 8; ++st) {
    f32x16 s0 = {}, s1 = {};
    __builtin_amdgcn_s_setprio(1);
    #pragma unroll
    for (int c = 0; c < 4; ++c) s0 = MFMA32(kf[c], qf[0][c], s0);
    #pragma unroll
    for (int c = 0; c < 4; ++c) s1 = MFMA32(kf[c], qf[1][c], s1);
    __builtin_amdgcn_s_setprio(0);
    if (st < 7) {                    // kf dead: reload now, lands during softmax+PV
      #pragma unroll
      for (int c = 0; c < 4; ++c)
        kf[c] = *(const short8*)(Kp + (size_t)(st + 1) * 2048 + c * 16);
    }
    process(s0, m0, ls0, o00, o10);
    process(s1, m1, ls1, o01, o11);
    if (st < 7) {                    // vf dead: reload, lands during next QK+softmax
      vf0[0] = *(const short8*)(Vp0 + (st + 1) * 32);
      vf0[1] = *(const short8*)(Vp0 + (st + 1) * 32 + 16);
      vf1[0] = *(const short8*)(Vp1 + (st + 1) * 32);
      vf1[1] = *(const short8*)(Vp1 + (st + 1) * 32 + 16);
    }
  }

  for (int half = 4; half > 0; half >>= 1) {
    const bool writer = (w >= half) && (w < 2 * half);
    const bool merger = (w < half);
    __syncthreads();
    if (writer && h == 0) {
      MpS[w - half][l31] = m0;      LpS[w - half][l31] = ls0;
      MpS[w - half][32 + l31] = m1; LpS[w - half][32 + l31] = ls1;
    }
    __syncthreads();
    float fb0 = 0.f, fb1 = 0.f;
    if (merger) {
      float pm0 = MpS[w][l31],      pl0 = LpS[w][l31];
      float pm1 = MpS[w][32 + l31], pl1 = LpS[w][32 + l31];
      float nm0 = fmaxf(m0, pm0), nm1 = fmaxf(m1, pm1);
      float fa0 = EXP2F(m0 - nm0); fb0 = EXP2F(pm0 - nm0);
      float fa1 = EXP2F(m1 - nm1); fb1 = EXP2F(pm1 - nm1);
      m0 = nm0; m1 = nm1;
      ls0 = ls0 * fa0 + pl0 * fb0; ls1 = ls1 * fa1 + pl1 * fb1;
      o00 *= fa0; o10 *= fa0; o01 *= fa1; o11 *= fa1;
    }
    __syncthreads();
    if (writer) {
      #pragma unroll
      for (int r = 0; r < 16; ++r) ObS[w - half][r][lane] = o00[r]; }
    __syncthreads();
    if (merger) {
      #pragma unroll
      for (int r = 0; r < 16; ++r) o00[r] += ObS[w][r][lane] * fb0; }
    __syncthreads();
    if (writer) {
      #pragma unroll
      for (int r = 0; r < 16; ++r) ObS[w - half][r][lane] = o01[r]; }
    __syncthreads();
    if (merger) {
      #pragma unroll
      for (int r = 0; r < 16; ++r) o01[r] += ObS[w][r][lane] * fb1; }
    __syncthreads();
    if (writer) {
      #pragma unroll
      for (int r = 0; r < 16; ++r) ObS[w - half][r][lane] = o10[r]; }
    __syncthreads();
    if (merger) {
      #pragma unroll
      for (int r = 0; r < 16; ++r) o10[r] += ObS[w][r][lane] * fb0; }
    __syncthreads();
    if (writer) {
      #pragma unroll
      for (int r = 0; r < 16; ++r) ObS[w - half][r][lane] = o11[r]; }
    __syncthreads();
    if (merger) {
      #pragma unroll
      for (int r = 0; r < 16; ++r) o11[r] += ObS[w][r][lane] * fb1; }
  }

  if (w == 0) {
    float i0 = 1.0f / ls0, i1 = 1.0f / ls1;
    o00 *= i0; o10 *= i0; o01 *= i1; o11 *= i1;
    #pragma unroll
    for (int qt = 0; qt < 2; ++qt) {
      int q = qt * 32 + l31;
      float* ob = out + ((size_t)(b * 2048 + q0 + q)) * 64 + 4 * h;
      const f32x16 a = qt ? o01 : o00;
      const f32x16 c = qt ? o11 : o10;
      #pragma unroll
      for (int g = 0; g < 4; ++g) {
        *(float4*)(ob + 8 * g)      = make_float4(a[4*g], a[4*g+1], a[4*g+2], a[4*g+3]);
        *(float4*)(ob + 32 + 8 * g) = make_float4(c[4*g], c[4*g+1], c[4*g+2], c[4*g+3]);
      }
    }
  }
}

extern "C" void kernel_launch(void* const* d_in, const int* in_sizes, int n_in,
                              void* d_out, int out_size, void* d_ws, size_t ws_size,
                              hipStream_t stream) {
  const float* qin = (const float*)d_in[0];
  const float* kin = (const float*)d_in[1];
  const float* vin = (const float*)d_in[2];
  const float* Wq  = (const float*)d_in[3];
  const float* bq  = (const float*)d_in[4];
  const float* Wk  = (const float*)d_in[5];
  const float* bk  = (const float*)d_in[6];
  const float* Wv  = (const float*)d_in[7];
  const float* bv  = (const float*)d_in[8];

  unsigned short* Qo  = (unsigned short*)d_ws;            // [8*2048][64] bf16 (pre-scaled)
  unsigned short* Ko  = Qo + (size_t)16384 * 64;          // [8*2048][64] bf16
  unsigned short* Vto = Ko + (size_t)16384 * 64;          // [8][64][2048] bf16 (transposed)
  unsigned short* Wt  = Vto + (size_t)8 * 64 * 2048;      // [3][64][512] bf16 W^T
  float* out = (float*)d_out;

  hipLaunchKernelGGL(prep_wt, dim3(384), dim3(256), 0, stream, Wq, Wk, Wv, Wt);
  hipLaunchKernelGGL(proj_kernel, dim3(256, 3), dim3(128), 0, stream,
                     qin, kin, vin, Wt, bq, bk, bv, Qo, Ko, Vto);
  hipLaunchKernelGGL(attn_kernel, dim3(32, 8), dim3(512), 0, stream, Qo, Ko, Vto, out);
}

// Round 8
// 163.824 us; speedup vs baseline: 1.0911x; 1.0911x over previous
//
#include <hip/hip_runtime.h>
#include <hip/hip_bf16.h>
#include <cstdint>

typedef __attribute__((ext_vector_type(8))) short short8;
typedef __attribute__((ext_vector_type(16))) float f32x16;

#if __has_builtin(__builtin_amdgcn_exp2f)
#define EXP2F(x) __builtin_amdgcn_exp2f(x)
#else
#define EXP2F(x) exp2f(x)
#endif

#define MFMA32(A, B, C) __builtin_amdgcn_mfma_f32_32x32x16_bf16((A), (B), (C), 0, 0, 0)

// fp32 -> bf16, round-to-nearest-even (proven path)
__device__ __forceinline__ unsigned short f2bf(float f) {
  unsigned int u = __builtin_bit_cast(unsigned int, f);
  u += 0x7FFFu + ((u >> 16) & 1u);
  return (unsigned short)(u >> 16);
}

// pack 8 fp32 (two float4) -> short8 bf16 A-fragment (proven bit pattern)
__device__ __forceinline__ short8 packA(const float4 &a0, const float4 &a1) {
  uint4 uu;
  uu.x = (unsigned int)f2bf(a0.x) | ((unsigned int)f2bf(a0.y) << 16);
  uu.y = (unsigned int)f2bf(a0.z) | ((unsigned int)f2bf(a0.w) << 16);
  uu.z = (unsigned int)f2bf(a1.x) | ((unsigned int)f2bf(a1.y) << 16);
  uu.w = (unsigned int)f2bf(a1.z) | ((unsigned int)f2bf(a1.w) << 16);
  return __builtin_bit_cast(short8, uu);
}

// ---------------------------------------------------------------------------
// Prep: Wt[which][n][k] = f2bf(W_which[k][n]),  3 x 64 x 512 bf16. (proven)
// ---------------------------------------------------------------------------
__global__ __launch_bounds__(256) void prep_wt(
    const float* __restrict__ Wq, const float* __restrict__ Wk,
    const float* __restrict__ Wv, unsigned short* __restrict__ Wt)
{
  int idx = blockIdx.x * 256 + threadIdx.x;     // 384 blocks
  int which = idx >> 15;
  int rem = idx & 32767;
  int n = rem >> 9;
  int k = rem & 511;
  const float* W = (which == 0) ? Wq : (which == 1) ? Wk : Wv;
  Wt[idx] = f2bf(W[k * 64 + n]);
}

// ---------------------------------------------------------------------------
// Projection, round 8: m97-faithful async staging.
//   r4-r7 lesson (3x confirmed): plain C loads get sunk by hipcc; no manual
//   pipeline survives. Fix = the one primitive it cannot sink:
//   __builtin_amdgcn_global_load_lds (async DMA, fire-and-forget), in the
//   measured-2.7TB/s m97 structure: fp32 chunks [64x64] (16KB), double
//   buffer, issue chunk c+1's 4 DMA calls BEFORE computing chunk c, one
//   vmcnt-draining __syncthreads per chunk. 3 blocks/CU overlap each
//   other's barrier drains (m114).
//   Swizzle (rule #21, both-sides-or-neither): gload_lds writes LINEAR
//   (lane*16B); the 16B slot within each 256B row is pre-swizzled at the
//   GLOBAL source (slot ^= row&15) and the same XOR is applied on the
//   ds_read address. Unswizzled would be a 32-way bank conflict (row
//   stride 256B); swizzled is 4-way (1.58x, off critical path).
//   Wave layout, k-order, C/D epilogue: byte-identical math to r3
//   (bitwise-same output). grid (256,3), 256 thr, LDS 32KB.
// ---------------------------------------------------------------------------
__global__ __launch_bounds__(256) void proj_kernel(
    const float* __restrict__ qin, const float* __restrict__ kin,
    const float* __restrict__ vin, const unsigned short* __restrict__ Wt,
    const float* __restrict__ bq, const float* __restrict__ bk,
    const float* __restrict__ bv,
    unsigned short* __restrict__ Qo, unsigned short* __restrict__ Ko,
    unsigned short* __restrict__ Vto)
{
  __shared__ float Xf[2][64 * 64];   // 2 x 16 KB; Xf[0] reused as TB for V

  const int which = blockIdx.y;
  const float* X    = (which == 0) ? qin : (which == 1) ? kin : vin;
  const float* bias = (which == 0) ? bq  : (which == 1) ? bk  : bv;

  const int tid = threadIdx.x;
  const int lane = tid & 63, wv = tid >> 6;
  const int h = lane >> 5, l31 = lane & 31;
  const int grp = wv & 1, nh = wv >> 1;
  const int m0 = blockIdx.x * 64;

  const unsigned short* wcol =
      Wt + (size_t)which * 32768 + (size_t)(nh * 32 + l31) * 512 + h * 8;

  // staging thread coords: per call k, thread covers row k*16 + (tid>>4),
  // physical 16B slot tid&15; content = logical slot (tid&15) ^ (row&15).
  const int srow4 = tid >> 4;        // 0..15
  const int sslot = tid & 15;

  // async DMA: 4 calls x 256 thr x 16B = 16KB chunk. LDS dest is linear
  // (wave-uniform base + lane*16); global src carries the swizzle.
  auto stage = [&](int chunk, int buf) {
    #pragma unroll
    for (int k = 0; k < 4; ++k) {
      const int row = k * 16 + srow4;
      const int l = sslot ^ (row & 15);
      const float* gp = X + (size_t)(m0 + row) * 512 + chunk * 64 + l * 4;
      char* lp = (char*)&Xf[buf][0] + k * 4096 + wv * 1024;   // wave-uniform
      __builtin_amdgcn_global_load_lds(
          (const __attribute__((address_space(1))) unsigned int*)gp,
          (__attribute__((address_space(3))) unsigned int*)lp, 16, 0, 0);
    }
  };

  stage(0, 0);
  __syncthreads();                                   // drains vmcnt: chunk 0 landed

  f32x16 acc = {};
  int buf = 0;
  #pragma unroll
  for (int c = 0; c < 8; ++c) {                      // 8 chunks of BK=64
    if (c < 7) stage(c + 1, buf ^ 1);                // fire-and-forget next chunk
    const int r = grp * 32 + l31;
    const float* arow = &Xf[buf][r * 64];
    const int rx = r & 15;
    const unsigned short* wk = wcol + c * 64;
    #pragma unroll
    for (int ks = 0; ks < 4; ++ks) {
      const int s0 = ks * 4 + h * 2;                 // logical 16B slot pair
      float4 x0 = *(const float4*)(arow + ((s0 ^ rx) * 4));
      float4 x1 = *(const float4*)(arow + (((s0 + 1) ^ rx) * 4));
      short8 af = packA(x0, x1);
      short8 bf = *(const short8*)(wk + ks * 16);
      acc = MFMA32(af, bf, acc);
    }
    __syncthreads();                                 // next chunk landed; buf free
    buf ^= 1;
  }

  const float bv0 = bias[nh * 32 + l31];

  if (which < 2) {
    const float scale = which ? 1.0f : 0.18033688f;  // (1/sqrt(64))*log2(e) for Q
    unsigned short* Y = which ? Ko : Qo;
    #pragma unroll
    for (int r = 0; r < 16; ++r) {
      int row = (r & 3) + 8 * (r >> 2) + 4 * h;      // C/D layout [m101]
      Y[(size_t)(m0 + grp * 32 + row) * 64 + nh * 32 + l31] =
          f2bf((acc[r] + bv0) * scale);
    }
  } else {
    __syncthreads();                // all waves past final chunk barrier
    unsigned short* TB = (unsigned short*)&Xf[0][0]; // [64 n][68 s], 8.7KB
    #pragma unroll
    for (int r = 0; r < 16; ++r) {
      int row = (r & 3) + 8 * (r >> 2) + 4 * h;
      TB[(nh * 32 + l31) * 68 + grp * 32 + row] = f2bf(acc[r] + bv0);
    }
    __syncthreads();
    int bidx = blockIdx.x >> 5;        // 32 blocks per batch (64 rows each)
    int s0 = (blockIdx.x & 31) * 64;
    for (int i = tid; i < 64 * 16; i += 256) {   // 64 n x 16 ushort4 chunks
      int n = i >> 4, cs = i & 15;
      ushort4 v4 = *(const ushort4*)(TB + n * 68 + cs * 4);
      *(ushort4*)(Vto + ((size_t)bidx * 64 + n) * 2048 + s0 + cs * 4) = v4;
    }
  }
}

// ---------------------------------------------------------------------------
// Flash attention, transposed formulation — exact round-3 proven version:
// tree reductions, defer-max (THR=8), K/V register prefetch, setprio,
// proven shfl_xor/f2bf exchange. 64 queries/block, grid (32,8).
// ---------------------------------------------------------------------------
__global__ __launch_bounds__(512, 2) void attn_kernel(
    const unsigned short* __restrict__ Q, const unsigned short* __restrict__ K,
    const unsigned short* __restrict__ Vt, float* __restrict__ out)
{
  __shared__ float ObS[4][16][64];
  __shared__ float MpS[4][64];
  __shared__ float LpS[4][64];

  const int tid = threadIdx.x;
  const int lane = tid & 63, w = tid >> 6;
  const int h = lane >> 5, l31 = lane & 31;
  const int b = blockIdx.y;
  const int q0 = blockIdx.x * 64;

  short8 qf[2][4];
  #pragma unroll
  for (int qt = 0; qt < 2; ++qt) {
    const unsigned short* qp = Q + ((size_t)(b * 2048 + q0 + qt * 32 + l31)) * 64 + h * 8;
    #pragma unroll
    for (int c = 0; c < 4; ++c) qf[qt][c] = *(const short8*)(qp + c * 16);
  }

  f32x16 o00 = {}, o01 = {}, o10 = {}, o11 = {};
  float m0 = -1e30f, m1 = -1e30f, ls0 = 0.f, ls1 = 0.f;

  const unsigned short* Kp  = K  + ((size_t)(b * 2048 + w * 256 + l31)) * 64 + h * 8;
  const unsigned short* Vp0 = Vt + ((size_t)(b * 64 + l31)) * 2048 + w * 256 + h * 8;
  const unsigned short* Vp1 = Vp0 + (size_t)32 * 2048;

  short8 kf[4], vf0[2], vf1[2];
  #pragma unroll
  for (int c = 0; c < 4; ++c) kf[c] = *(const short8*)(Kp + c * 16);
  vf0[0] = *(const short8*)(Vp0); vf0[1] = *(const short8*)(Vp0 + 16);
  vf1[0] = *(const short8*)(Vp1); vf1[1] = *(const short8*)(Vp1 + 16);

  // softmax + PV for one 32-query tile; sT is S^T[key r][q l31]
  auto process = [&](f32x16 sT, float &m, float &ls, f32x16 &oA, f32x16 &oB) {
    float tm[8];
    #pragma unroll
    for (int i = 0; i < 8; ++i) tm[i] = fmaxf(sT[2 * i], sT[2 * i + 1]);
    #pragma unroll
    for (int i = 0; i < 4; ++i) tm[i] = fmaxf(tm[i], tm[i + 4]);
    float mx = fmaxf(fmaxf(tm[0], tm[1]), fmaxf(tm[2], tm[3]));
    mx = fmaxf(mx, __shfl_xor(mx, 32, 64));
    if (__any(mx > m + 8.0f)) {   // defer-max (log2 domain, P <= 2^8)
      float mnew = fmaxf(m, mx);
      float alpha = EXP2F(m - mnew);
      m = mnew;
      ls *= alpha; oA *= alpha; oB *= alpha;
    }
    float p[16];
    #pragma unroll
    for (int r = 0; r < 16; ++r) p[r] = EXP2F(sT[r] - m);
    float ts[8];
    #pragma unroll
    for (int i = 0; i < 8; ++i) ts[i] = p[2 * i] + p[2 * i + 1];
    #pragma unroll
    for (int i = 0; i < 4; ++i) ts[i] += ts[i + 4];
    float rs = (ts[0] + ts[1]) + (ts[2] + ts[3]);
    rs += __shfl_xor(rs, 32, 64);
    ls += rs;
    unsigned int pk[8];
    #pragma unroll
    for (int i = 0; i < 8; ++i)
      pk[i] = (unsigned int)f2bf(p[2 * i]) | ((unsigned int)f2bf(p[2 * i + 1]) << 16);
    unsigned int ex[8];
    #pragma unroll
    for (int i = 0; i < 8; ++i) ex[i] = (unsigned int)__shfl_xor((int)pk[i], 32, 64);
    uint4 cc0, cc1;
    if (h == 0) { cc0 = make_uint4(pk[0], pk[1], ex[0], ex[1]); cc1 = make_uint4(pk[4], pk[5], ex[4], ex[5]); }
    else        { cc0 = make_uint4(ex[2], ex[3], pk[2], pk[3]); cc1 = make_uint4(ex[6], ex[7], pk[6], pk[7]); }
    short8 P0 = __builtin_bit_cast(short8, cc0);
    short8 P1 = __builtin_bit_cast(short8, cc1);
    __builtin_amdgcn_s_setprio(1);
    oA = MFMA32(vf0[0], P0, oA); oA = MFMA32(vf0[1], P1, oA);
    oB = MFMA32(vf1[0], P0, oB); oB = MFMA32(vf1[1], P1, oB);
    __builtin_amdgcn_s_setprio(0);
  };

  for (int st = 0; st < 8; ++st) {
    f32x16 s0 = {}, s1 = {};
    __builtin_amdgcn_s_setprio(1);
    #pragma unroll
    for (int c = 0; c < 4; ++c) s0 = MFMA32(kf[c], qf[0][c], s0);
    #pragma unroll
    for (int c = 0; c < 4; ++c) s1 = MFMA32(kf[c], qf[1][c], s1);
    __builtin_amdgcn_s_setprio(0);
    if (st < 7) {                    // kf dead: reload now, lands during softmax+PV
      #pragma unroll
      for (int c = 0; c < 4; ++c)
        kf[c] = *(const short8*)(Kp + (size_t)(st + 1) * 2048 + c * 16);
    }
    process(s0, m0, ls0, o00, o10);
    process(s1, m1, ls1, o01, o11);
    if (st < 7) {                    // vf dead: reload, lands during next QK+softmax
      vf0[0] = *(const short8*)(Vp0 + (st + 1) * 32);
      vf0[1] = *(const short8*)(Vp0 + (st + 1) * 32 + 16);
      vf1[0] = *(const short8*)(Vp1 + (st + 1) * 32);
      vf1[1] = *(const short8*)(Vp1 + (st + 1) * 32 + 16);
    }
  }

  for (int half = 4; half > 0; half >>= 1) {
    const bool writer = (w >= half) && (w < 2 * half);
    const bool merger = (w < half);
    __syncthreads();
    if (writer && h == 0) {
      MpS[w - half][l31] = m0;      LpS[w - half][l31] = ls0;
      MpS[w - half][32 + l31] = m1; LpS[w - half][32 + l31] = ls1;
    }
    __syncthreads();
    float fb0 = 0.f, fb1 = 0.f;
    if (merger) {
      float pm0 = MpS[w][l31],      pl0 = LpS[w][l31];
      float pm1 = MpS[w][32 + l31], pl1 = LpS[w][32 + l31];
      float nm0 = fmaxf(m0, pm0), nm1 = fmaxf(m1, pm1);
      float fa0 = EXP2F(m0 - nm0); fb0 = EXP2F(pm0 - nm0);
      float fa1 = EXP2F(m1 - nm1); fb1 = EXP2F(pm1 - nm1);
      m0 = nm0; m1 = nm1;
      ls0 = ls0 * fa0 + pl0 * fb0; ls1 = ls1 * fa1 + pl1 * fb1;
      o00 *= fa0; o10 *= fa0; o01 *= fa1; o11 *= fa1;
    }
    __syncthreads();
    if (writer) {
      #pragma unroll
      for (int r = 0; r < 16; ++r) ObS[w - half][r][lane] = o00[r]; }
    __syncthreads();
    if (merger) {
      #pragma unroll
      for (int r = 0; r < 16; ++r) o00[r] += ObS[w][r][lane] * fb0; }
    __syncthreads();
    if (writer) {
      #pragma unroll
      for (int r = 0; r < 16; ++r) ObS[w - half][r][lane] = o01[r]; }
    __syncthreads();
    if (merger) {
      #pragma unroll
      for (int r = 0; r < 16; ++r) o01[r] += ObS[w][r][lane] * fb1; }
    __syncthreads();
    if (writer) {
      #pragma unroll
      for (int r = 0; r < 16; ++r) ObS[w - half][r][lane] = o10[r]; }
    __syncthreads();
    if (merger) {
      #pragma unroll
      for (int r = 0; r < 16; ++r) o10[r] += ObS[w][r][lane] * fb0; }
    __syncthreads();
    if (writer) {
      #pragma unroll
      for (int r = 0; r < 16; ++r) ObS[w - half][r][lane] = o11[r]; }
    __syncthreads();
    if (merger) {
      #pragma unroll
      for (int r = 0; r < 16; ++r) o11[r] += ObS[w][r][lane] * fb1; }
  }

  if (w == 0) {
    float i0 = 1.0f / ls0, i1 = 1.0f / ls1;
    o00 *= i0; o10 *= i0; o01 *= i1; o11 *= i1;
    #pragma unroll
    for (int qt = 0; qt < 2; ++qt) {
      int q = qt * 32 + l31;
      float* ob = out + ((size_t)(b * 2048 + q0 + q)) * 64 + 4 * h;
      const f32x16 a = qt ? o01 : o00;
      const f32x16 c = qt ? o11 : o10;
      #pragma unroll
      for (int g = 0; g < 4; ++g) {
        *(float4*)(ob + 8 * g)      = make_float4(a[4*g], a[4*g+1], a[4*g+2], a[4*g+3]);
        *(float4*)(ob + 32 + 8 * g) = make_float4(c[4*g], c[4*g+1], c[4*g+2], c[4*g+3]);
      }
    }
  }
}

extern "C" void kernel_launch(void* const* d_in, const int* in_sizes, int n_in,
                              void* d_out, int out_size, void* d_ws, size_t ws_size,
                              hipStream_t stream) {
  const float* qin = (const float*)d_in[0];
  const float* kin = (const float*)d_in[1];
  const float* vin = (const float*)d_in[2];
  const float* Wq  = (const float*)d_in[3];
  const float* bq  = (const float*)d_in[4];
  const float* Wk  = (const float*)d_in[5];
  const float* bk  = (const float*)d_in[6];
  const float* Wv  = (const float*)d_in[7];
  const float* bv  = (const float*)d_in[8];

  unsigned short* Qo  = (unsigned short*)d_ws;            // [8*2048][64] bf16 (pre-scaled)
  unsigned short* Ko  = Qo + (size_t)16384 * 64;          // [8*2048][64] bf16
  unsigned short* Vto = Ko + (size_t)16384 * 64;          // [8][64][2048] bf16 (transposed)
  unsigned short* Wt  = Vto + (size_t)8 * 64 * 2048;      // [3][64][512] bf16 W^T
  float* out = (float*)d_out;

  hipLaunchKernelGGL(prep_wt, dim3(384), dim3(256), 0, stream, Wq, Wk, Wv, Wt);
  hipLaunchKernelGGL(proj_kernel, dim3(256, 3), dim3(256), 0, stream,
                     qin, kin, vin, Wt, bq, bk, bv, Qo, Ko, Vto);
  hipLaunchKernelGGL(attn_kernel, dim3(32, 8), dim3(512), 0, stream, Qo, Ko, Vto, out);
}